// Round 20
// baseline (724.340 us; speedup 1.0000x reference)
//
#include <hip/hip_runtime.h>
#include <math.h>

#define B 32
#define T 512
#define D 256
#define H 8
#define DH 32
#define MF 128
#define NLAYER 6
#define FF 1024
#define NM 4
#define BT (B*T)
#define BH (B*H)

#define DN2H 0.08838834764831845f   /* 0.5 * 32^-0.5 (0.5*dn^2) */
#define DNS  0.4204482076268573f    /* 32^-0.25 */
#define RATIO 0.08838834764831845f  /* 128^-0.5 */
#define KEPS 1e-4f

typedef __attribute__((ext_vector_type(8))) short short8;
typedef __attribute__((ext_vector_type(4))) float f32x4;

#define MFMA(a, b, c) __builtin_amdgcn_mfma_f32_16x16x32_bf16(a, b, c, 0, 0, 0)

// swizzled 16B-group (element offset) a staging lane fetches from global
#define SWZG(l) (((((l) & 3) + (((l) >> 3) & 3)) & 3) * 8)
// LDS element offset of logical 16B-group gi for row-in-chunk li (inverse swizzle)
#define RS(li, gi) (((((gi) - ((li) >> 1)) & 3)) * 8)

#define WAIT_VM(N) asm volatile("s_waitcnt vmcnt(" #N ")" ::: "memory")

__device__ __forceinline__ ushort f2b(float x) {
  union { float f; unsigned u; } c; c.f = x;
  unsigned r = (c.u + 0x7FFFu + ((c.u >> 16) & 1u)) >> 16;
  return (ushort)r;
}
__device__ __forceinline__ float bf2f(ushort u) {
  union { unsigned u; float f; } c; c.u = ((unsigned)u) << 16;
  return c.f;
}
__device__ __forceinline__ void gload16(const ushort* g, ushort* l) {
  __builtin_amdgcn_global_load_lds((const __attribute__((address_space(1))) void*)g,
                                   (__attribute__((address_space(3))) void*)l, 16, 0, 0);
}

// ---------------- transpose mel (B,D,T) -> x (B,T,D) fp32 ----------------
__global__ void transpose_mel(const float* __restrict__ mel, float* __restrict__ x) {
  __shared__ float tile[32][33];
  int b = blockIdx.z;
  int d0 = blockIdx.y * 32, t0 = blockIdx.x * 32;
  int tx = threadIdx.x, ty = threadIdx.y;
  #pragma unroll
  for (int i = 0; i < 32; i += 8)
    tile[ty + i][tx] = mel[(b * D + d0 + ty + i) * T + t0 + tx];
  __syncthreads();
  #pragma unroll
  for (int i = 0; i < 32; i += 8)
    x[(b * T + t0 + ty + i) * D + d0 + tx] = tile[tx][ty + i];
}

// ---------------- weight transpose+convert: W[K][N] fp32 -> WT[N][K] bf16 ----------------
__global__ void wtrans(const float* __restrict__ W, ushort* __restrict__ WT,
                       int K, int N, size_t lin, size_t lout) {
  __shared__ float tile[32][33];
  int l = blockIdx.z;
  const float* Wl = W + (size_t)l * lin;
  ushort* WTl = WT + (size_t)l * lout;
  int k0 = blockIdx.y * 32, n0 = blockIdx.x * 32;
  int tx = threadIdx.x, ty = threadIdx.y;
  #pragma unroll
  for (int i = 0; i < 32; i += 8)
    tile[ty + i][tx] = Wl[(size_t)(k0 + ty + i) * N + n0 + tx];
  __syncthreads();
  #pragma unroll
  for (int i = 0; i < 32; i += 8)
    WTl[(size_t)(n0 + ty + i) * K + k0 + tx] = f2b(tile[tx][ty + i]);
}

// ---------------- proj convert (prescaled by DN) ----------------
__global__ void proj_conv(const float* __restrict__ proj, ushort* __restrict__ projd) {
  int e = blockIdx.x * 256 + threadIdx.x;
  if (e < MF * DH) projd[e] = f2b(proj[e] * DNS);
}

// ---------------- layernorm (layer-0 entry only) ----------------
__global__ __launch_bounds__(256) void ln_kernel(const float* __restrict__ x, const float* __restrict__ g,
                          const float* __restrict__ bb, ushort* __restrict__ y) {
  int row = blockIdx.x * 4 + (threadIdx.x >> 6);
  int lane = threadIdx.x & 63;
  const float4 v = ((const float4*)(x + (size_t)row * D))[lane];
  float s = v.x + v.y + v.z + v.w;
  #pragma unroll
  for (int off = 32; off; off >>= 1) s += __shfl_down(s, off);
  s = __shfl(s, 0);
  float mu = s * (1.0f / 256.0f);
  float dx = v.x - mu, dy = v.y - mu, dz = v.z - mu, dw = v.w - mu;
  float q = dx * dx + dy * dy + dz * dz + dw * dw;
  #pragma unroll
  for (int off = 32; off; off >>= 1) q += __shfl_down(q, off);
  q = __shfl(q, 0);
  float rstd = rsqrtf(q * (1.0f / 256.0f) + 1e-5f);
  const float4 gg = ((const float4*)g)[lane];
  const float4 be = ((const float4*)bb)[lane];
  ushort4 o;
  o.x = f2b(dx * rstd * gg.x + be.x);
  o.y = f2b(dy * rstd * gg.y + be.y);
  o.z = f2b(dz * rstd * gg.z + be.z);
  o.w = f2b(dw * rstd * gg.w + be.w);
  ((ushort4*)(y + (size_t)row * D))[lane] = o;
}

// ---------------- bf16 MFMA GEMM (layer-0 QKV), dbuf + counted-vmcnt ----------------
template<int EPI, int BM>
__global__ __launch_bounds__(256) void gemm_bf16(
    const ushort* __restrict__ A, const ushort* __restrict__ BTm,
    const float* __restrict__ bias,
    ushort* __restrict__ outB,
    ushort* __restrict__ qo, ushort* __restrict__ ko, ushort* __restrict__ vT,
    int N, int K) {
  constexpr int MFR = BM / 32;
  __shared__ __align__(16) ushort Al[2][BM * 32];
  __shared__ __align__(16) ushort Bl[2][128 * 32];
  int tid = threadIdx.x;
  int wave = tid >> 6, lane = tid & 63;
  int wr = wave >> 1, wc = wave & 1;
  int gi = lane >> 4, li = lane & 15;
  int lrow = lane >> 2, lkb = SWZG(lane);
  int row0 = blockIdx.y * BM, col0 = blockIdx.x * 128;
  f32x4 acc[MFR][4] = {};

  auto stage = [&](int buf, int kk) {
    #pragma unroll
    for (int i = 0; i < BM / 64; i++) {
      int chunk = wave * (BM / 64) + i;
      gload16(&A[(size_t)(row0 + chunk * 16 + lrow) * K + kk + lkb], &Al[buf][chunk * 512]);
    }
    #pragma unroll
    for (int i = 0; i < 2; i++) {
      int chunk = wave * 2 + i;
      gload16(&BTm[(size_t)(col0 + chunk * 16 + lrow) * K + kk + lkb], &Bl[buf][chunk * 512]);
    }
  };

  stage(0, 0);
  int cur = 0;
  for (int k0 = 0; k0 < K; k0 += 32, cur ^= 1) {
    if (k0 + 32 < K) {
      stage(cur ^ 1, k0 + 32);
      if (BM == 64) { WAIT_VM(3); } else { WAIT_VM(4); }
    } else {
      WAIT_VM(0);
    }
    __builtin_amdgcn_s_barrier();
    __builtin_amdgcn_sched_barrier(0);
    short8 a[MFR], b[4];
    #pragma unroll
    for (int m = 0; m < MFR; m++)
      a[m] = *(const short8*)&Al[cur][(wr * (MFR * 16) + m * 16 + li) * 32 + RS(li, gi)];
    #pragma unroll
    for (int n = 0; n < 4; n++)
      b[n] = *(const short8*)&Bl[cur][(wc * 64 + n * 16 + li) * 32 + RS(li, gi)];
    #pragma unroll
    for (int m = 0; m < MFR; m++)
      #pragma unroll
      for (int n = 0; n < 4; n++)
        acc[m][n] = MFMA(a[m], b[n], acc[m][n]);
    __builtin_amdgcn_s_barrier();
  }
  #pragma unroll
  for (int m = 0; m < MFR; m++) {
    int rbase = row0 + wr * (MFR * 16) + m * 16 + gi * 4;
    #pragma unroll
    for (int n = 0; n < 4; n++) {
      int col = col0 + wc * 64 + n * 16 + li;
      f32x4 v = acc[m][n];
      if (EPI == 2) {
        float bs = bias[col];
        #pragma unroll
        for (int r = 0; r < 4; r++) {
          float u = v[r] + bs;
          float p = u + 0.044715f * u * u * u;
          float gel = u / (1.0f + __expf(-1.5957691216057308f * p));
          outB[(size_t)(rbase + r) * N + col] = f2b(gel);
        }
      } else {
        if (col < 256) {
          #pragma unroll
          for (int r = 0; r < 4; r++) qo[(size_t)(rbase + r) * 256 + col] = f2b(v[r]);
        } else if (col < 512) {
          #pragma unroll
          for (int r = 0; r < 4; r++) ko[(size_t)(rbase + r) * 256 + col - 256] = f2b(v[r]);
        } else {
          int b_ = rbase >> 9, t = rbase & 511;
          int hh = (col - 512) >> 5, d = (col - 512) & 31;
          ushort4 pk;
          pk.x = f2b(v[0]); pk.y = f2b(v[1]); pk.z = f2b(v[2]); pk.w = f2b(v[3]);
          *(ushort4*)&vT[((size_t)((b_ * 8 + hh) * 32 + d)) * 512 + t] = pk;
        }
      }
    }
  }
}

// ---------------- fused k-features + ctx per (b,h) ----------------
__global__ __launch_bounds__(256) void ctx_fused(
    const ushort* __restrict__ kb, const ushort* __restrict__ projd,
    const ushort* __restrict__ vT, ushort* __restrict__ Bmat) {
  __shared__ __align__(16) ushort Kl[512 * 32];
  __shared__ __align__(16) ushort Pl[128 * 32];
  __shared__ __align__(16) ushort Sl[2][128 * 40];
  __shared__ __align__(16) ushort Bvl[2][32 * 32];
  __shared__ float dg_s[512];
  __shared__ float red_s[256];
  int bh = blockIdx.x;
  int b = bh >> 3, h = bh & 7;
  int tid = threadIdx.x, wave = tid >> 6, lane = tid & 63;
  int gi = lane >> 4, li = lane & 15;
  int lrow = lane >> 2, lkb = (lane & 3) * 8;
  const ushort* Kg = kb + (size_t)(b * 512) * 256 + h * 32;
  const ushort* Vg = vT + (size_t)bh * 32 * 512;
  #pragma unroll
  for (int i = 0; i < 8; i++) {
    int chunk = wave * 8 + i;
    gload16(&Kg[(size_t)(chunk * 16 + lrow) * 256 + lkb], &Kl[chunk * 512]);
  }
  #pragma unroll
  for (int i = 0; i < 2; i++) {
    int chunk = wave * 2 + i;
    gload16(&projd[(chunk * 16 + lrow) * 32 + lkb], &Pl[chunk * 512]);
  }
  __syncthreads();
  #pragma unroll
  for (int i = 0; i < 2; i++) {
    int t = tid * 2 + i;
    const ushort* kr = &Kl[t * 32];
    float s = 0.f;
    #pragma unroll
    for (int j = 0; j < 32; j++) { float v = bf2f(kr[j]); s += v * v; }
    dg_s[t] = DN2H * s;
  }
  short8 bp0 = *(const short8*)&Pl[(wave * 32 + li) * 32 + gi * 8];
  short8 bp1 = *(const short8*)&Pl[(wave * 32 + 16 + li) * 32 + gi * 8];
  float smax = -1e30f;
  for (int c = 0; c < 16; c++) {
    int t0c = c * 32;
    short8 a0 = *(const short8*)&Kl[(t0c + li) * 32 + gi * 8];
    short8 a1 = *(const short8*)&Kl[(t0c + 16 + li) * 32 + gi * 8];
    f32x4 s00 = {}, s01 = {}, s10 = {}, s11 = {};
    s00 = MFMA(a0, bp0, s00); s01 = MFMA(a0, bp1, s01);
    s10 = MFMA(a1, bp0, s10); s11 = MFMA(a1, bp1, s11);
    #pragma unroll
    for (int r = 0; r < 4; r++)
      smax = fmaxf(smax, fmaxf(fmaxf(s00[r], s01[r]), fmaxf(s10[r], s11[r])));
  }
  red_s[tid] = smax;
  __syncthreads();
  for (int s = 128; s; s >>= 1) {
    if (tid < s) red_s[tid] = fmaxf(red_s[tid], red_s[tid + s]);
    __syncthreads();
  }
  float km = red_s[0];
  f32x4 cacc[2][2] = {};
  float ks0 = 0.f, ks1 = 0.f;
  int cur = 0;
  for (int c = 0; c < 16; c++, cur ^= 1) {
    int t0c = c * 32;
    if (wave < 2)
      gload16(&Vg[(size_t)(wave * 16 + lrow) * 512 + t0c + lkb], &Bvl[cur][wave * 512]);
    short8 a0 = *(const short8*)&Kl[(t0c + li) * 32 + gi * 8];
    short8 a1 = *(const short8*)&Kl[(t0c + 16 + li) * 32 + gi * 8];
    f32x4 s00 = {}, s01 = {}, s10 = {}, s11 = {};
    s00 = MFMA(a0, bp0, s00); s01 = MFMA(a0, bp1, s01);
    s10 = MFMA(a1, bp0, s10); s11 = MFMA(a1, bp1, s11);
    ushort4 w00, w01, w10, w11;
    #pragma unroll
    for (int r = 0; r < 4; r++) {
      float d0 = dg_s[t0c + gi * 4 + r];
      float d1 = dg_s[t0c + 16 + gi * 4 + r];
      float k00 = RATIO * (__expf(s00[r] - d0 - km) + KEPS);
      float k01 = RATIO * (__expf(s01[r] - d0 - km) + KEPS);
      float k10 = RATIO * (__expf(s10[r] - d1 - km) + KEPS);
      float k11 = RATIO * (__expf(s11[r] - d1 - km) + KEPS);
      ks0 += k00 + k10; ks1 += k01 + k11;
      ((ushort*)&w00)[r] = f2b(k00); ((ushort*)&w01)[r] = f2b(k01);
      ((ushort*)&w10)[r] = f2b(k10); ((ushort*)&w11)[r] = f2b(k11);
    }
    *(ushort4*)&Sl[cur][(wave * 32 + li) * 40 + gi * 4]           = w00;
    *(ushort4*)&Sl[cur][(wave * 32 + 16 + li) * 40 + gi * 4]      = w01;
    *(ushort4*)&Sl[cur][(wave * 32 + li) * 40 + 16 + gi * 4]      = w10;
    *(ushort4*)&Sl[cur][(wave * 32 + 16 + li) * 40 + 16 + gi * 4] = w11;
    __syncthreads();
    short8 ca0 = *(const short8*)&Sl[cur][(wave * 32 + li) * 40 + gi * 8];
    short8 ca1 = *(const short8*)&Sl[cur][(wave * 32 + 16 + li) * 40 + gi * 8];
    short8 cb0 = *(const short8*)&Bvl[cur][li * 32 + gi * 8];
    short8 cb1 = *(const short8*)&Bvl[cur][(16 + li) * 32 + gi * 8];
    cacc[0][0] = MFMA(ca0, cb0, cacc[0][0]);
    cacc[0][1] = MFMA(ca0, cb1, cacc[0][1]);
    cacc[1][0] = MFMA(ca1, cb0, cacc[1][0]);
    cacc[1][1] = MFMA(ca1, cb1, cacc[1][1]);
  }
  ks0 += __shfl_xor(ks0, 16); ks0 += __shfl_xor(ks0, 32);
  ks1 += __shfl_xor(ks1, 16); ks1 += __shfl_xor(ks1, 32);
  if (gi == 0) {
    Bmat[((size_t)bh * 48 + 32) * 128 + wave * 32 + li] = f2b(ks0);
    Bmat[((size_t)bh * 48 + 32) * 128 + wave * 32 + 16 + li] = f2b(ks1);
  }
  #pragma unroll
  for (int m = 0; m < 2; m++)
    #pragma unroll
    for (int n = 0; n < 2; n++) {
      int dd = n * 16 + li;
      int mg = wave * 32 + m * 16 + gi * 4;
      ushort4 pk;
      pk.x = f2b(cacc[m][n][0]); pk.y = f2b(cacc[m][n][1]);
      pk.z = f2b(cacc[m][n][2]); pk.w = f2b(cacc[m][n][3]);
      *(ushort4*)&Bmat[((size_t)bh * 48 + dd) * 128 + mg] = pk;
    }
  for (int e = tid; e < 15 * 128; e += 256)
    Bmat[((size_t)bh * 48 + 33) * 128 + e] = 0;
}

// ---------------- fused q-features + o per (64 t, bh) ----------------
__global__ __launch_bounds__(256) void favq_o(
    const ushort* __restrict__ qb, const ushort* __restrict__ projd,
    const ushort* __restrict__ Bmat, ushort* __restrict__ ob) {
  __shared__ __align__(16) ushort Ql[64 * 32];
  __shared__ __align__(16) ushort Pl[128 * 32];
  __shared__ __align__(16) ushort Sl[64 * 136];
  __shared__ __align__(16) ushort Bml[48 * 136];
  __shared__ float dgq[64];
  int bh = blockIdx.y;
  int t0 = blockIdx.x * 64;
  int b = bh >> 3, h = bh & 7;
  int tid = threadIdx.x, wave = tid >> 6, lane = tid & 63;
  int gi = lane >> 4, li = lane & 15;
  int lrow = lane >> 2, lkb = (lane & 3) * 8;
  const ushort* Qg = qb + (size_t)(b * 512) * 256 + h * 32;
  gload16(&Qg[(size_t)(t0 + wave * 16 + lrow) * 256 + lkb], &Ql[wave * 512]);
  #pragma unroll
  for (int i = 0; i < 2; i++) {
    int chunk = wave * 2 + i;
    gload16(&projd[(chunk * 16 + lrow) * 32 + lkb], &Pl[chunk * 512]);
  }
  #pragma unroll
  for (int j = 0; j < 3; j++) {
    int c = j * 256 + tid;
    int r = c >> 4, g = c & 15;
    *(uint4*)&Bml[r * 136 + g * 8] = *(const uint4*)&Bmat[(size_t)bh * 48 * 128 + r * 128 + g * 8];
  }
  __syncthreads();
  if (tid < 64) {
    const ushort* qr = &Ql[tid * 32];
    float s = 0.f;
    #pragma unroll
    for (int j = 0; j < 32; j++) { float v = bf2f(qr[j]); s += v * v; }
    dgq[tid] = DN2H * s;
  }
  short8 bq = *(const short8*)&Ql[(wave * 16 + li) * 32 + gi * 8];
  f32x4 sacc[8] = {};
  #pragma unroll
  for (int m = 0; m < 8; m++) {
    short8 a = *(const short8*)&Pl[(m * 16 + li) * 32 + gi * 8];
    sacc[m] = MFMA(a, bq, sacc[m]);
  }
  __syncthreads();
  float mx = -1e30f;
  #pragma unroll
  for (int m = 0; m < 8; m++)
    #pragma unroll
    for (int r = 0; r < 4; r++) mx = fmaxf(mx, sacc[m][r]);
  mx = fmaxf(mx, __shfl_xor(mx, 16));
  mx = fmaxf(mx, __shfl_xor(mx, 32));
  float dg = dgq[wave * 16 + li];
  #pragma unroll
  for (int m = 0; m < 8; m++) {
    ushort4 o4;
    #pragma unroll
    for (int r = 0; r < 4; r++)
      ((ushort*)&o4)[r] = f2b(RATIO * (__expf(sacc[m][r] - dg - mx) + KEPS));
    *(ushort4*)&Sl[(wave * 16 + li) * 136 + m * 16 + gi * 4] = o4;
  }
  __syncthreads();
  f32x4 oacc[3] = {};
  #pragma unroll
  for (int ks = 0; ks < 4; ks++) {
    short8 a = *(const short8*)&Sl[(wave * 16 + li) * 136 + ks * 32 + gi * 8];
    #pragma unroll
    for (int n = 0; n < 3; n++) {
      short8 bb = *(const short8*)&Bml[(n * 16 + li) * 136 + ks * 32 + gi * 8];
      oacc[n] = MFMA(a, bb, oacc[n]);
    }
  }
  int t = t0 + wave * 16 + gi * 4;
  float den[4];
  #pragma unroll
  for (int r = 0; r < 4; r++) den[r] = __shfl(oacc[2][r], lane & 48);
  #pragma unroll
  for (int n = 0; n < 2; n++)
    #pragma unroll
    for (int r = 0; r < 4; r++)
      ob[((size_t)(b * 512) + t + r) * 256 + h * 32 + n * 16 + li] = f2b(oacc[n][r] / den[r]);
}

// ---------------- fused Wo-GEMM + LN + FF1 (3-deep B, fully static unroll) ----------------
__global__ __launch_bounds__(256) void wo_ff1(
    const ushort* __restrict__ ob, const ushort* __restrict__ woT,
    const float* __restrict__ bo, const float* __restrict__ res, float* __restrict__ x,
    const float* __restrict__ g, const float* __restrict__ bvec,
    const ushort* __restrict__ w1T, const float* __restrict__ b1v,
    ushort* __restrict__ ffh) {
  __shared__ __align__(16) ushort U[8 * 1024];       // phase1 Apr[4][2][1024] | phase2 Hp
  __shared__ __align__(16) ushort Bpr[4][3][2048];   // per-wave B 3-deep (64x32)
  __shared__ float rs1[4 * 32], rs2[4 * 32];
  int tid = threadIdx.x, wave = tid >> 6, lane = tid & 63;
  int gi = lane >> 4, li = lane & 15;
  int lrow = lane >> 2, lkb = SWZG(lane);
  int row0 = blockIdx.x * 32;
  f32x4 acc[2][4] = {};
  ushort* Apr = &U[wave * 2048];
  ushort* Hp  = &U[0];

  // ---- phase 1: Wo GEMM, K=256, 8 steps, A 2-deep + B 3-deep ----
  auto stageA1 = [&](int buf, int st) {
    #pragma unroll
    for (int i = 0; i < 2; i++)
      gload16(&ob[(size_t)(row0 + i * 16 + lrow) * 256 + st * 32 + lkb], &Apr[buf * 1024 + i * 512]);
  };
  auto stageB1 = [&](int buf, int st) {
    #pragma unroll
    for (int i = 0; i < 4; i++)
      gload16(&woT[(size_t)(wave * 64 + i * 16 + lrow) * 256 + st * 32 + lkb], &Bpr[wave][buf][i * 512]);
  };
  stageA1(0, 0); stageB1(0, 0); stageB1(1, 1);
  #pragma unroll
  for (int st = 0; st < 8; st++) {
    if (st + 1 < 8) stageA1((st + 1) & 1, st + 1);
    if (st + 2 < 8) { stageB1((st + 2) % 3, st + 2); WAIT_VM(10); }
    else if (st + 1 < 8) { WAIT_VM(6); }
    else { WAIT_VM(0); }
    __builtin_amdgcn_sched_barrier(0);
    short8 a[2], b[4];
    #pragma unroll
    for (int m = 0; m < 2; m++)
      a[m] = *(const short8*)&Apr[(st & 1) * 1024 + (m * 16 + li) * 32 + RS(li, gi)];
    #pragma unroll
    for (int n = 0; n < 4; n++)
      b[n] = *(const short8*)&Bpr[wave][st % 3][(n * 16 + li) * 32 + RS(li, gi)];
    __builtin_amdgcn_s_setprio(1);
    #pragma unroll
    for (int m = 0; m < 2; m++)
      #pragma unroll
      for (int n = 0; n < 4; n++)
        acc[m][n] = MFMA(a[m], b[n], acc[m][n]);
    __builtin_amdgcn_s_setprio(0);
  }
  // epilogue A: bias+res, partial sums
  #pragma unroll
  for (int m = 0; m < 2; m++) {
    #pragma unroll
    for (int r = 0; r < 4; r++) {
      int row = row0 + m * 16 + gi * 4 + r;
      int ridx = m * 16 + gi * 4 + r;
      float s1 = 0.f, s2 = 0.f;
      #pragma unroll
      for (int n = 0; n < 4; n++) {
        int col = wave * 64 + n * 16 + li;
        float val = acc[m][n][r] + bo[col] + res[(size_t)row * 256 + col];
        acc[m][n][r] = val;
        s1 += val; s2 += val * val;
      }
      #pragma unroll
      for (int off = 1; off <= 8; off <<= 1) { s1 += __shfl_xor(s1, off); s2 += __shfl_xor(s2, off); }
      if (li == 0) { rs1[wave * 32 + ridx] = s1; rs2[wave * 32 + ridx] = s2; }
    }
  }
  __syncthreads();   // all phase-1 Apr reads done; U becomes Hp
  // epilogue B: LN -> x fp32 + Hp panel
  {
    float g4[4], bv4[4];
    #pragma unroll
    for (int n = 0; n < 4; n++) {
      int col = wave * 64 + n * 16 + li;
      g4[n] = g[col]; bv4[n] = bvec[col];
    }
    #pragma unroll
    for (int m = 0; m < 2; m++) {
      #pragma unroll
      for (int r = 0; r < 4; r++) {
        int row32 = m * 16 + gi * 4 + r;
        int row = row0 + row32;
        float t1 = rs1[row32] + rs1[32 + row32] + rs1[64 + row32] + rs1[96 + row32];
        float t2 = rs2[row32] + rs2[32 + row32] + rs2[64 + row32] + rs2[96 + row32];
        float mu = t1 * (1.f / 256.f);
        float rstd = rsqrtf(t2 * (1.f / 256.f) - mu * mu + 1e-5f);
        #pragma unroll
        for (int n = 0; n < 4; n++) {
          int col = wave * 64 + n * 16 + li;
          float val = acc[m][n][r];
          x[(size_t)row * 256 + col] = val;
          float hv = (val - mu) * rstd * g4[n] + bv4[n];
          int kc = col >> 5, c32 = col & 31;
          int G = c32 >> 3, c7 = c32 & 7;
          int slot = (G - (row32 >> 1)) & 3;
          Hp[kc * 1024 + row32 * 32 + slot * 8 + c7] = f2b(hv);
        }
      }
    }
  }
  // ---- phase 2: FF1 from Hp panel, B 3-deep, static unroll ----
  auto stageB2 = [&](int buf, int st) {
    int nc = st >> 3, ks = st & 7;
    #pragma unroll
    for (int i = 0; i < 4; i++)
      gload16(&w1T[(size_t)(nc * 256 + wave * 64 + i * 16 + lrow) * 256 + ks * 32 + lkb],
              &Bpr[wave][buf][i * 512]);
  };
  stageB2(0, 0); stageB2(1, 1);
  __syncthreads();   // Hp visible to all waves
  f32x4 fac[2][4] = {};
  #pragma unroll
  for (int st = 0; st < 32; st++) {
    int nc = st >> 3, ks = st & 7;
    if (st + 2 < 32) { stageB2((st + 2) % 3, st + 2); WAIT_VM(8); }
    else if (st + 1 < 32) { WAIT_VM(4); }
    else { WAIT_VM(0); }
    __builtin_amdgcn_sched_barrier(0);
    short8 a[2], b[4];
    #pragma unroll
    for (int m = 0; m < 2; m++)
      a[m] = *(const short8*)&Hp[ks * 1024 + (m * 16 + li) * 32 + RS(li, gi)];
    #pragma unroll
    for (int n = 0; n < 4; n++)
      b[n] = *(const short8*)&Bpr[wave][st % 3][(n * 16 + li) * 32 + RS(li, gi)];
    __builtin_amdgcn_s_setprio(1);
    #pragma unroll
    for (int m = 0; m < 2; m++)
      #pragma unroll
      for (int n = 0; n < 4; n++)
        fac[m][n] = MFMA(a[m], b[n], fac[m][n]);
    __builtin_amdgcn_s_setprio(0);
    if (ks == 7) {
      #pragma unroll
      for (int m = 0; m < 2; m++) {
        int rbase = row0 + m * 16 + gi * 4;
        #pragma unroll
        for (int n = 0; n < 4; n++) {
          int col = nc * 256 + wave * 64 + n * 16 + li;
          float bs = b1v[col];
          #pragma unroll
          for (int r = 0; r < 4; r++) {
            float u = fac[m][n][r] + bs;
            float p = u + 0.044715f * u * u * u;
            float gel = u / (1.0f + __expf(-1.5957691216057308f * p));
            ffh[(size_t)(rbase + r) * 1024 + col] = f2b(gel);
            fac[m][n][r] = 0.f;
          }
        }
      }
    }
  }
}

// ---------------- fused FF2-GEMM + LN + next-layer QKV (3-deep B, static unroll) ----------------
__global__ __launch_bounds__(256) void ff2_qkv(
    const ushort* __restrict__ ffh, const ushort* __restrict__ w2T,
    const float* __restrict__ b2v, const float* __restrict__ res, float* __restrict__ x,
    const float* __restrict__ g, const float* __restrict__ bvec,
    const ushort* __restrict__ qkvT,
    ushort* __restrict__ qo, ushort* __restrict__ ko, ushort* __restrict__ vT) {
  __shared__ __align__(16) ushort U[8 * 1024];
  __shared__ __align__(16) ushort Bpr[4][3][2048];
  __shared__ float rs1[4 * 32], rs2[4 * 32];
  int tid = threadIdx.x, wave = tid >> 6, lane = tid & 63;
  int gi = lane >> 4, li = lane & 15;
  int lrow = lane >> 2, lkb = SWZG(lane);
  int row0 = blockIdx.x * 32;
  f32x4 acc[2][4] = {};
  ushort* Apr = &U[wave * 2048];
  ushort* Hp  = &U[0];

  // ---- phase 1: FF2 GEMM, K=1024, 32 steps, A 2-deep + B 3-deep ----
  auto stageA1 = [&](int buf, int st) {
    #pragma unroll
    for (int i = 0; i < 2; i++)
      gload16(&ffh[(size_t)(row0 + i * 16 + lrow) * 1024 + st * 32 + lkb], &Apr[buf * 1024 + i * 512]);
  };
  auto stageB1 = [&](int buf, int st) {
    #pragma unroll
    for (int i = 0; i < 4; i++)
      gload16(&w2T[(size_t)(wave * 64 + i * 16 + lrow) * 1024 + st * 32 + lkb], &Bpr[wave][buf][i * 512]);
  };
  stageA1(0, 0); stageB1(0, 0); stageB1(1, 1);
  #pragma unroll
  for (int st = 0; st < 32; st++) {
    if (st + 1 < 32) stageA1((st + 1) & 1, st + 1);
    if (st + 2 < 32) { stageB1((st + 2) % 3, st + 2); WAIT_VM(10); }
    else if (st + 1 < 32) { WAIT_VM(6); }
    else { WAIT_VM(0); }
    __builtin_amdgcn_sched_barrier(0);
    short8 a[2], b[4];
    #pragma unroll
    for (int m = 0; m < 2; m++)
      a[m] = *(const short8*)&Apr[(st & 1) * 1024 + (m * 16 + li) * 32 + RS(li, gi)];
    #pragma unroll
    for (int n = 0; n < 4; n++)
      b[n] = *(const short8*)&Bpr[wave][st % 3][(n * 16 + li) * 32 + RS(li, gi)];
    __builtin_amdgcn_s_setprio(1);
    #pragma unroll
    for (int m = 0; m < 2; m++)
      #pragma unroll
      for (int n = 0; n < 4; n++)
        acc[m][n] = MFMA(a[m], b[n], acc[m][n]);
    __builtin_amdgcn_s_setprio(0);
  }
  #pragma unroll
  for (int m = 0; m < 2; m++) {
    #pragma unroll
    for (int r = 0; r < 4; r++) {
      int row = row0 + m * 16 + gi * 4 + r;
      int ridx = m * 16 + gi * 4 + r;
      float s1 = 0.f, s2 = 0.f;
      #pragma unroll
      for (int n = 0; n < 4; n++) {
        int col = wave * 64 + n * 16 + li;
        float val = acc[m][n][r] + b2v[col] + res[(size_t)row * 256 + col];
        acc[m][n][r] = val;
        s1 += val; s2 += val * val;
      }
      #pragma unroll
      for (int off = 1; off <= 8; off <<= 1) { s1 += __shfl_xor(s1, off); s2 += __shfl_xor(s2, off); }
      if (li == 0) { rs1[wave * 32 + ridx] = s1; rs2[wave * 32 + ridx] = s2; }
    }
  }
  __syncthreads();   // all phase-1 Apr reads done; U becomes Hp
  {
    float g4[4], bv4[4];
    #pragma unroll
    for (int n = 0; n < 4; n++) {
      int col = wave * 64 + n * 16 + li;
      g4[n] = g[col]; bv4[n] = bvec[col];
    }
    #pragma unroll
    for (int m = 0; m < 2; m++) {
      #pragma unroll
      for (int r = 0; r < 4; r++) {
        int row32 = m * 16 + gi * 4 + r;
        int row = row0 + row32;
        float t1 = rs1[row32] + rs1[32 + row32] + rs1[64 + row32] + rs1[96 + row32];
        float t2 = rs2[row32] + rs2[32 + row32] + rs2[64 + row32] + rs2[96 + row32];
        float mu = t1 * (1.f / 256.f);
        float rstd = rsqrtf(t2 * (1.f / 256.f) - mu * mu + 1e-5f);
        #pragma unroll
        for (int n = 0; n < 4; n++) {
          int col = wave * 64 + n * 16 + li;
          float val = acc[m][n][r];
          x[(size_t)row * 256 + col] = val;
          float hv = (val - mu) * rstd * g4[n] + bv4[n];
          int kc = col >> 5, c32 = col & 31;
          int G = c32 >> 3, c7 = c32 & 7;
          int slot = (G - (row32 >> 1)) & 3;
          Hp[kc * 1024 + row32 * 32 + slot * 8 + c7] = f2b(hv);
        }
      }
    }
  }
  // ---- phase 2: QKV from Hp panel (N=768), B 3-deep, static unroll ----
  auto stageB2 = [&](int buf, int st) {
    int nc = st >> 3, ks = st & 7;
    #pragma unroll
    for (int i = 0; i < 4; i++)
      gload16(&qkvT[(size_t)(nc * 256 + wave * 64 + i * 16 + lrow) * 256 + ks * 32 + lkb],
              &Bpr[wave][buf][i * 512]);
  };
  stageB2(0, 0); stageB2(1, 1);
  __syncthreads();
  f32x4 fac[2][4] = {};
  #pragma unroll
  for (int st = 0; st < 24; st++) {
    int nc = st >> 3, ks = st & 7;
    if (st + 2 < 24) { stageB2((st + 2) % 3, st + 2); WAIT_VM(8); }
    else if (st + 1 < 24) { WAIT_VM(4); }
    else { WAIT_VM(0); }
    __builtin_amdgcn_sched_barrier(0);
    short8 a[2], b[4];
    #pragma unroll
    for (int m = 0; m < 2; m++)
      a[m] = *(const short8*)&Hp[ks * 1024 + (m * 16 + li) * 32 + RS(li, gi)];
    #pragma unroll
    for (int n = 0; n < 4; n++)
      b[n] = *(const short8*)&Bpr[wave][st % 3][(n * 16 + li) * 32 + RS(li, gi)];
    __builtin_amdgcn_s_setprio(1);
    #pragma unroll
    for (int m = 0; m < 2; m++)
      #pragma unroll
      for (int n = 0; n < 4; n++)
        fac[m][n] = MFMA(a[m], b[n], fac[m][n]);
    __builtin_amdgcn_s_setprio(0);
    if (ks == 7) {
      #pragma unroll
      for (int m = 0; m < 2; m++) {
        int rbase = row0 + m * 16 + gi * 4;
        #pragma unroll
        for (int n = 0; n < 4; n++) {
          int col256 = wave * 64 + n * 16 + li;
          if (nc == 0) {
            #pragma unroll
            for (int r = 0; r < 4; r++) { qo[(size_t)(rbase + r) * 256 + col256] = f2b(fac[m][n][r]); fac[m][n][r] = 0.f; }
          } else if (nc == 1) {
            #pragma unroll
            for (int r = 0; r < 4; r++) { ko[(size_t)(rbase + r) * 256 + col256] = f2b(fac[m][n][r]); fac[m][n][r] = 0.f; }
          } else {
            int b_ = rbase >> 9, t = rbase & 511;
            int hh = col256 >> 5, d = col256 & 31;
            ushort4 pk;
            pk.x = f2b(fac[m][n][0]); pk.y = f2b(fac[m][n][1]);
            pk.z = f2b(fac[m][n][2]); pk.w = f2b(fac[m][n][3]);
            *(ushort4*)&vT[((size_t)((b_ * 8 + hh) * 32 + d)) * 512 + t] = pk;
            fac[m][n][0] = fac[m][n][1] = fac[m][n][2] = fac[m][n][3] = 0.f;
          }
        }
      }
    }
  }
}

// ---------------- GEMM 32x256 + bias + residual + mask (final layer FF2) ----------------
__global__ __launch_bounds__(256) void gemm_mask(
    const ushort* __restrict__ A, const ushort* __restrict__ BTm,
    const float* __restrict__ bias, const float* __restrict__ res,
    const float* __restrict__ Wm, const float* __restrict__ bm, float* __restrict__ mout,
    int K) {
  __shared__ __align__(16) ushort Al[2][32 * 32];
  __shared__ __align__(16) ushort Bl[2][256 * 32];
  __shared__ float pmS[4 * 128];
  int tid = threadIdx.x, wave = tid >> 6, lane = tid & 63;
  int gi = lane >> 4, li = lane & 15;
  int lrow = lane >> 2, lkb = SWZG(lane);
  int row0 = blockIdx.x * 32;
  int wc = wave;
  f32x4 acc[2][4] = {};

  auto stage = [&](int buf, int kk) {
    if (wave < 2)
      gload16(&A[(size_t)(row0 + wave * 16 + lrow) * K + kk + lkb], &Al[buf][wave * 512]);
    #pragma unroll
    for (int i = 0; i < 4; i++) {
      int chunk = wave * 4 + i;
      gload16(&BTm[(size_t)(chunk * 16 + lrow) * K + kk + lkb], &Bl[buf][chunk * 512]);
    }
  };
  stage(0, 0);
  __syncthreads();
  int cur = 0;
  for (int k0 = 0; k0 < K; k0 += 32, cur ^= 1) {
    if (k0 + 32 < K) stage(cur ^ 1, k0 + 32);
    short8 a[2], b[4];
    #pragma unroll
    for (int m = 0; m < 2; m++)
      a[m] = *(const short8*)&Al[cur][(m * 16 + li) * 32 + RS(li, gi)];
    #pragma unroll
    for (int n = 0; n < 4; n++)
      b[n] = *(const short8*)&Bl[cur][(wc * 64 + n * 16 + li) * 32 + RS(li, gi)];
    #pragma unroll
    for (int m = 0; m < 2; m++)
      #pragma unroll
      for (int n = 0; n < 4; n++)
        acc[m][n] = MFMA(a[m], b[n], acc[m][n]);
    __syncthreads();
  }
  #pragma unroll
  for (int m = 0; m < 2; m++) {
    #pragma unroll
    for (int r = 0; r < 4; r++) {
      int row = row0 + m * 16 + gi * 4 + r;
      int ridx = m * 16 + gi * 4 + r;
      #pragma unroll
      for (int n = 0; n < 4; n++) {
        int col = wc * 64 + n * 16 + li;
        acc[m][n][r] += bias[col] + res[(size_t)row * 256 + col];
      }
      #pragma unroll
      for (int msk = 0; msk < NM; msk++) {
        float sm = 0.f;
        #pragma unroll
        for (int n = 0; n < 4; n++) {
          int col = wc * 64 + n * 16 + li;
          sm += acc[m][n][r] * Wm[col * NM + msk];
        }
        #pragma unroll
        for (int off = 1; off <= 8; off <<= 1) sm += __shfl_xor(sm, off);
        if (li == 0) pmS[wave * 128 + ridx * 4 + msk] = sm;
      }
    }
  }
  __syncthreads();
  if (tid < 128) {
    int ridx = tid >> 2, msk = tid & 3;
    float tot = pmS[ridx * 4 + msk] + pmS[128 + ridx * 4 + msk] +
                pmS[256 + ridx * 4 + msk] + pmS[384 + ridx * 4 + msk];
    int grow = row0 + ridx;
    int bb_ = grow >> 9, t = grow & 511;
    mout[((size_t)(bb_ * NM) + msk) * 512 + t] = tot + bm[msk];
  }
}

extern "C" void kernel_launch(void* const* d_in, const int* in_sizes, int n_in,
                              void* d_out, int out_size, void* d_ws, size_t ws_size,
                              hipStream_t stream) {
  const float* mel   = (const float*)d_in[0];
  const float* proj  = (const float*)d_in[1];
  const float* ln1_g = (const float*)d_in[2];
  const float* ln1_b = (const float*)d_in[3];
  const float* Wq    = (const float*)d_in[4];
  const float* Wk    = (const float*)d_in[5];
  const float* Wv    = (const float*)d_in[6];
  const float* Wo    = (const float*)d_in[7];
  const float* bo    = (const float*)d_in[8];
  const float* ln2_g = (const float*)d_in[9];
  const float* ln2_b = (const float*)d_in[10];
  const float* W1    = (const float*)d_in[11];
  const float* b1    = (const float*)d_in[12];
  const float* W2    = (const float*)d_in[13];
  const float* b2    = (const float*)d_in[14];
  const float* Wm    = (const float*)d_in[15];
  const float* bm    = (const float*)d_in[16];

  // ---- workspace layout ----
  float* x      = (float*)d_ws;                        // BT*D fp32
  ushort* us    = (ushort*)(x + (size_t)BT * D);
  ushort* h     = us;                   us += (size_t)BT * D;
  ushort* qb    = us;                   us += (size_t)BT * D;
  ushort* kb    = us;                   us += (size_t)BT * D;
  ushort* vT    = us;                   us += (size_t)BH * 32 * T;
  ushort* ob    = us;                   us += (size_t)BT * D;
  ushort* ffh   = us;                   us += (size_t)BT * FF;
  ushort* Bmat  = us;                   us += (size_t)BH * 48 * MF;
  ushort* qkvT  = us;                   us += (size_t)NLAYER * 768 * 256;
  ushort* woT   = us;                   us += (size_t)NLAYER * 256 * 256;
  ushort* w1T   = us;                   us += (size_t)NLAYER * 1024 * 256;
  ushort* w2T   = us;                   us += (size_t)NLAYER * 256 * 1024;
  ushort* projd = us;                   us += (size_t)MF * DH;

  // ---- prep: transposed bf16 weights ----
  wtrans<<<dim3(8, 8, NLAYER), dim3(32, 8), 0, stream>>>(Wq, qkvT, 256, 256, 65536, 768 * 256);
  wtrans<<<dim3(8, 8, NLAYER), dim3(32, 8), 0, stream>>>(Wk, qkvT + 256 * 256, 256, 256, 65536, 768 * 256);
  wtrans<<<dim3(8, 8, NLAYER), dim3(32, 8), 0, stream>>>(Wv, qkvT + 512 * 256, 256, 256, 65536, 768 * 256);
  wtrans<<<dim3(8, 8, NLAYER), dim3(32, 8), 0, stream>>>(Wo, woT, 256, 256, 65536, 65536);
  wtrans<<<dim3(32, 8, NLAYER), dim3(32, 8), 0, stream>>>(W1, w1T, 256, 1024, 262144, 262144);
  wtrans<<<dim3(8, 32, NLAYER), dim3(32, 8), 0, stream>>>(W2, w2T, 1024, 256, 262144, 262144);
  proj_conv<<<16, 256, 0, stream>>>(proj, projd);

  transpose_mel<<<dim3(T / 32, D / 32, B), dim3(32, 8), 0, stream>>>(mel, x);
  ln_kernel<<<BT / 4, 256, 0, stream>>>(x, ln1_g, ln1_b, h);

  // layer-0 QKV from global h
  gemm_bf16<0, 64><<<dim3(6, 256), 256, 0, stream>>>(h, qkvT,
      nullptr, nullptr, qb, kb, vT, 768, 256);

  for (int l = 0; l < NLAYER; l++) {
    ctx_fused<<<BH, 256, 0, stream>>>(kb, projd, vT, Bmat);
    favq_o<<<dim3(8, BH), 256, 0, stream>>>(qb, projd, Bmat, ob);
    wo_ff1<<<BT / 32, 256, 0, stream>>>(ob, woT + (size_t)l * 256 * 256,
        bo + l * D, x, x, ln2_g + l * D, ln2_b + l * D,
        w1T + (size_t)l * 1024 * 256, b1 + (size_t)l * FF, ffh);
    if (l < NLAYER - 1) {
      ff2_qkv<<<BT / 32, 256, 0, stream>>>(ffh, w2T + (size_t)l * 256 * 1024,
          b2 + l * D, x, x, ln1_g + (l + 1) * D, ln1_b + (l + 1) * D,
          qkvT + (size_t)(l + 1) * 768 * 256, qb, kb, vT);
    } else {
      gemm_mask<<<BT / 32, 256, 0, stream>>>(ffh, w2T + (size_t)l * 256 * 1024,
          b2 + l * D, x, Wm, bm, (float*)d_out, 1024);
    }
  }
}

// Round 21
// 698.097 us; speedup vs baseline: 1.0376x; 1.0376x over previous
//
#include <hip/hip_runtime.h>
#include <math.h>

#define B 32
#define T 512
#define D 256
#define H 8
#define DH 32
#define MF 128
#define NLAYER 6
#define FF 1024
#define NM 4
#define BT (B*T)
#define BH (B*H)

#define DN2H 0.08838834764831845f   /* 0.5 * 32^-0.5 (0.5*dn^2) */
#define DNS  0.4204482076268573f    /* 32^-0.25 */
#define RATIO 0.08838834764831845f  /* 128^-0.5 */
#define KEPS 1e-4f

typedef __attribute__((ext_vector_type(8))) short short8;
typedef __attribute__((ext_vector_type(4))) float f32x4;

#define MFMA(a, b, c) __builtin_amdgcn_mfma_f32_16x16x32_bf16(a, b, c, 0, 0, 0)

// swizzled 16B-group (element offset) a staging lane fetches from global
#define SWZG(l) (((((l) & 3) + (((l) >> 3) & 3)) & 3) * 8)
// LDS element offset of logical 16B-group gi for row-in-chunk li (inverse swizzle)
#define RS(li, gi) (((((gi) - ((li) >> 1)) & 3)) * 8)

#define WAIT_VM(N) asm volatile("s_waitcnt vmcnt(" #N ")" ::: "memory")

__device__ __forceinline__ ushort f2b(float x) {
  union { float f; unsigned u; } c; c.f = x;
  unsigned r = (c.u + 0x7FFFu + ((c.u >> 16) & 1u)) >> 16;
  return (ushort)r;
}
__device__ __forceinline__ float bf2f(ushort u) {
  union { unsigned u; float f; } c; c.u = ((unsigned)u) << 16;
  return c.f;
}
__device__ __forceinline__ void gload16(const ushort* g, ushort* l) {
  __builtin_amdgcn_global_load_lds((const __attribute__((address_space(1))) void*)g,
                                   (__attribute__((address_space(3))) void*)l, 16, 0, 0);
}

// ---------------- transpose mel (B,D,T) -> x (B,T,D) fp32 ----------------
__global__ void transpose_mel(const float* __restrict__ mel, float* __restrict__ x) {
  __shared__ float tile[32][33];
  int b = blockIdx.z;
  int d0 = blockIdx.y * 32, t0 = blockIdx.x * 32;
  int tx = threadIdx.x, ty = threadIdx.y;
  #pragma unroll
  for (int i = 0; i < 32; i += 8)
    tile[ty + i][tx] = mel[(b * D + d0 + ty + i) * T + t0 + tx];
  __syncthreads();
  #pragma unroll
  for (int i = 0; i < 32; i += 8)
    x[(b * T + t0 + ty + i) * D + d0 + tx] = tile[tx][ty + i];
}

// ---------------- weight transpose+convert: W[K][N] fp32 -> WT[N][K] bf16 ----------------
__global__ void wtrans(const float* __restrict__ W, ushort* __restrict__ WT,
                       int K, int N, size_t lin, size_t lout) {
  __shared__ float tile[32][33];
  int l = blockIdx.z;
  const float* Wl = W + (size_t)l * lin;
  ushort* WTl = WT + (size_t)l * lout;
  int k0 = blockIdx.y * 32, n0 = blockIdx.x * 32;
  int tx = threadIdx.x, ty = threadIdx.y;
  #pragma unroll
  for (int i = 0; i < 32; i += 8)
    tile[ty + i][tx] = Wl[(size_t)(k0 + ty + i) * N + n0 + tx];
  __syncthreads();
  #pragma unroll
  for (int i = 0; i < 32; i += 8)
    WTl[(size_t)(n0 + ty + i) * K + k0 + tx] = f2b(tile[tx][ty + i]);
}

// ---------------- proj convert (prescaled by DN) ----------------
__global__ void proj_conv(const float* __restrict__ proj, ushort* __restrict__ projd) {
  int e = blockIdx.x * 256 + threadIdx.x;
  if (e < MF * DH) projd[e] = f2b(proj[e] * DNS);
}

// ---------------- layernorm (layer-0 entry only) ----------------
__global__ __launch_bounds__(256) void ln_kernel(const float* __restrict__ x, const float* __restrict__ g,
                          const float* __restrict__ bb, ushort* __restrict__ y) {
  int row = blockIdx.x * 4 + (threadIdx.x >> 6);
  int lane = threadIdx.x & 63;
  const float4 v = ((const float4*)(x + (size_t)row * D))[lane];
  float s = v.x + v.y + v.z + v.w;
  #pragma unroll
  for (int off = 32; off; off >>= 1) s += __shfl_down(s, off);
  s = __shfl(s, 0);
  float mu = s * (1.0f / 256.0f);
  float dx = v.x - mu, dy = v.y - mu, dz = v.z - mu, dw = v.w - mu;
  float q = dx * dx + dy * dy + dz * dz + dw * dw;
  #pragma unroll
  for (int off = 32; off; off >>= 1) q += __shfl_down(q, off);
  q = __shfl(q, 0);
  float rstd = rsqrtf(q * (1.0f / 256.0f) + 1e-5f);
  const float4 gg = ((const float4*)g)[lane];
  const float4 be = ((const float4*)bb)[lane];
  ushort4 o;
  o.x = f2b(dx * rstd * gg.x + be.x);
  o.y = f2b(dy * rstd * gg.y + be.y);
  o.z = f2b(dz * rstd * gg.z + be.z);
  o.w = f2b(dw * rstd * gg.w + be.w);
  ((ushort4*)(y + (size_t)row * D))[lane] = o;
}

// ---------------- bf16 MFMA GEMM (layer-0 QKV), dbuf + counted-vmcnt ----------------
template<int EPI, int BM>
__global__ __launch_bounds__(256) void gemm_bf16(
    const ushort* __restrict__ A, const ushort* __restrict__ BTm,
    const float* __restrict__ bias,
    ushort* __restrict__ outB,
    ushort* __restrict__ qo, ushort* __restrict__ ko, ushort* __restrict__ vT,
    int N, int K) {
  constexpr int MFR = BM / 32;
  __shared__ __align__(16) ushort Al[2][BM * 32];
  __shared__ __align__(16) ushort Bl[2][128 * 32];
  int tid = threadIdx.x;
  int wave = tid >> 6, lane = tid & 63;
  int wr = wave >> 1, wc = wave & 1;
  int gi = lane >> 4, li = lane & 15;
  int lrow = lane >> 2, lkb = SWZG(lane);
  int row0 = blockIdx.y * BM, col0 = blockIdx.x * 128;
  f32x4 acc[MFR][4] = {};

  auto stage = [&](int buf, int kk) {
    #pragma unroll
    for (int i = 0; i < BM / 64; i++) {
      int chunk = wave * (BM / 64) + i;
      gload16(&A[(size_t)(row0 + chunk * 16 + lrow) * K + kk + lkb], &Al[buf][chunk * 512]);
    }
    #pragma unroll
    for (int i = 0; i < 2; i++) {
      int chunk = wave * 2 + i;
      gload16(&BTm[(size_t)(col0 + chunk * 16 + lrow) * K + kk + lkb], &Bl[buf][chunk * 512]);
    }
  };

  stage(0, 0);
  int cur = 0;
  for (int k0 = 0; k0 < K; k0 += 32, cur ^= 1) {
    if (k0 + 32 < K) {
      stage(cur ^ 1, k0 + 32);
      if (BM == 64) { WAIT_VM(3); } else { WAIT_VM(4); }
    } else {
      WAIT_VM(0);
    }
    __builtin_amdgcn_s_barrier();
    __builtin_amdgcn_sched_barrier(0);
    short8 a[MFR], b[4];
    #pragma unroll
    for (int m = 0; m < MFR; m++)
      a[m] = *(const short8*)&Al[cur][(wr * (MFR * 16) + m * 16 + li) * 32 + RS(li, gi)];
    #pragma unroll
    for (int n = 0; n < 4; n++)
      b[n] = *(const short8*)&Bl[cur][(wc * 64 + n * 16 + li) * 32 + RS(li, gi)];
    #pragma unroll
    for (int m = 0; m < MFR; m++)
      #pragma unroll
      for (int n = 0; n < 4; n++)
        acc[m][n] = MFMA(a[m], b[n], acc[m][n]);
    __builtin_amdgcn_s_barrier();
  }
  #pragma unroll
  for (int m = 0; m < MFR; m++) {
    int rbase = row0 + wr * (MFR * 16) + m * 16 + gi * 4;
    #pragma unroll
    for (int n = 0; n < 4; n++) {
      int col = col0 + wc * 64 + n * 16 + li;
      f32x4 v = acc[m][n];
      if (EPI == 2) {
        float bs = bias[col];
        #pragma unroll
        for (int r = 0; r < 4; r++) {
          float u = v[r] + bs;
          float p = u + 0.044715f * u * u * u;
          float gel = u / (1.0f + __expf(-1.5957691216057308f * p));
          outB[(size_t)(rbase + r) * N + col] = f2b(gel);
        }
      } else {
        if (col < 256) {
          #pragma unroll
          for (int r = 0; r < 4; r++) qo[(size_t)(rbase + r) * 256 + col] = f2b(v[r]);
        } else if (col < 512) {
          #pragma unroll
          for (int r = 0; r < 4; r++) ko[(size_t)(rbase + r) * 256 + col - 256] = f2b(v[r]);
        } else {
          int b_ = rbase >> 9, t = rbase & 511;
          int hh = (col - 512) >> 5, d = (col - 512) & 31;
          ushort4 pk;
          pk.x = f2b(v[0]); pk.y = f2b(v[1]); pk.z = f2b(v[2]); pk.w = f2b(v[3]);
          *(ushort4*)&vT[((size_t)((b_ * 8 + hh) * 32 + d)) * 512 + t] = pk;
        }
      }
    }
  }
}

// ---------------- fused k-features + ctx per (b,h) ----------------
__global__ __launch_bounds__(256) void ctx_fused(
    const ushort* __restrict__ kb, const ushort* __restrict__ projd,
    const ushort* __restrict__ vT, ushort* __restrict__ Bmat) {
  __shared__ __align__(16) ushort Kl[512 * 32];
  __shared__ __align__(16) ushort Pl[128 * 32];
  __shared__ __align__(16) ushort Sl[2][128 * 40];
  __shared__ __align__(16) ushort Bvl[2][32 * 32];
  __shared__ float dg_s[512];
  __shared__ float red_s[256];
  int bh = blockIdx.x;
  int b = bh >> 3, h = bh & 7;
  int tid = threadIdx.x, wave = tid >> 6, lane = tid & 63;
  int gi = lane >> 4, li = lane & 15;
  int lrow = lane >> 2, lkb = (lane & 3) * 8;
  const ushort* Kg = kb + (size_t)(b * 512) * 256 + h * 32;
  const ushort* Vg = vT + (size_t)bh * 32 * 512;
  #pragma unroll
  for (int i = 0; i < 8; i++) {
    int chunk = wave * 8 + i;
    gload16(&Kg[(size_t)(chunk * 16 + lrow) * 256 + lkb], &Kl[chunk * 512]);
  }
  #pragma unroll
  for (int i = 0; i < 2; i++) {
    int chunk = wave * 2 + i;
    gload16(&projd[(chunk * 16 + lrow) * 32 + lkb], &Pl[chunk * 512]);
  }
  __syncthreads();
  #pragma unroll
  for (int i = 0; i < 2; i++) {
    int t = tid * 2 + i;
    const ushort* kr = &Kl[t * 32];
    float s = 0.f;
    #pragma unroll
    for (int j = 0; j < 32; j++) { float v = bf2f(kr[j]); s += v * v; }
    dg_s[t] = DN2H * s;
  }
  short8 bp0 = *(const short8*)&Pl[(wave * 32 + li) * 32 + gi * 8];
  short8 bp1 = *(const short8*)&Pl[(wave * 32 + 16 + li) * 32 + gi * 8];
  float smax = -1e30f;
  for (int c = 0; c < 16; c++) {
    int t0c = c * 32;
    short8 a0 = *(const short8*)&Kl[(t0c + li) * 32 + gi * 8];
    short8 a1 = *(const short8*)&Kl[(t0c + 16 + li) * 32 + gi * 8];
    f32x4 s00 = {}, s01 = {}, s10 = {}, s11 = {};
    s00 = MFMA(a0, bp0, s00); s01 = MFMA(a0, bp1, s01);
    s10 = MFMA(a1, bp0, s10); s11 = MFMA(a1, bp1, s11);
    #pragma unroll
    for (int r = 0; r < 4; r++)
      smax = fmaxf(smax, fmaxf(fmaxf(s00[r], s01[r]), fmaxf(s10[r], s11[r])));
  }
  red_s[tid] = smax;
  __syncthreads();
  for (int s = 128; s; s >>= 1) {
    if (tid < s) red_s[tid] = fmaxf(red_s[tid], red_s[tid + s]);
    __syncthreads();
  }
  float km = red_s[0];
  f32x4 cacc[2][2] = {};
  float ks0 = 0.f, ks1 = 0.f;
  int cur = 0;
  for (int c = 0; c < 16; c++, cur ^= 1) {
    int t0c = c * 32;
    if (wave < 2)
      gload16(&Vg[(size_t)(wave * 16 + lrow) * 512 + t0c + lkb], &Bvl[cur][wave * 512]);
    short8 a0 = *(const short8*)&Kl[(t0c + li) * 32 + gi * 8];
    short8 a1 = *(const short8*)&Kl[(t0c + 16 + li) * 32 + gi * 8];
    f32x4 s00 = {}, s01 = {}, s10 = {}, s11 = {};
    s00 = MFMA(a0, bp0, s00); s01 = MFMA(a0, bp1, s01);
    s10 = MFMA(a1, bp0, s10); s11 = MFMA(a1, bp1, s11);
    ushort4 w00, w01, w10, w11;
    #pragma unroll
    for (int r = 0; r < 4; r++) {
      float d0 = dg_s[t0c + gi * 4 + r];
      float d1 = dg_s[t0c + 16 + gi * 4 + r];
      float k00 = RATIO * (__expf(s00[r] - d0 - km) + KEPS);
      float k01 = RATIO * (__expf(s01[r] - d0 - km) + KEPS);
      float k10 = RATIO * (__expf(s10[r] - d1 - km) + KEPS);
      float k11 = RATIO * (__expf(s11[r] - d1 - km) + KEPS);
      ks0 += k00 + k10; ks1 += k01 + k11;
      ((ushort*)&w00)[r] = f2b(k00); ((ushort*)&w01)[r] = f2b(k01);
      ((ushort*)&w10)[r] = f2b(k10); ((ushort*)&w11)[r] = f2b(k11);
    }
    *(ushort4*)&Sl[cur][(wave * 32 + li) * 40 + gi * 4]           = w00;
    *(ushort4*)&Sl[cur][(wave * 32 + 16 + li) * 40 + gi * 4]      = w01;
    *(ushort4*)&Sl[cur][(wave * 32 + li) * 40 + 16 + gi * 4]      = w10;
    *(ushort4*)&Sl[cur][(wave * 32 + 16 + li) * 40 + 16 + gi * 4] = w11;
    __syncthreads();
    short8 ca0 = *(const short8*)&Sl[cur][(wave * 32 + li) * 40 + gi * 8];
    short8 ca1 = *(const short8*)&Sl[cur][(wave * 32 + 16 + li) * 40 + gi * 8];
    short8 cb0 = *(const short8*)&Bvl[cur][li * 32 + gi * 8];
    short8 cb1 = *(const short8*)&Bvl[cur][(16 + li) * 32 + gi * 8];
    cacc[0][0] = MFMA(ca0, cb0, cacc[0][0]);
    cacc[0][1] = MFMA(ca0, cb1, cacc[0][1]);
    cacc[1][0] = MFMA(ca1, cb0, cacc[1][0]);
    cacc[1][1] = MFMA(ca1, cb1, cacc[1][1]);
  }
  ks0 += __shfl_xor(ks0, 16); ks0 += __shfl_xor(ks0, 32);
  ks1 += __shfl_xor(ks1, 16); ks1 += __shfl_xor(ks1, 32);
  if (gi == 0) {
    Bmat[((size_t)bh * 48 + 32) * 128 + wave * 32 + li] = f2b(ks0);
    Bmat[((size_t)bh * 48 + 32) * 128 + wave * 32 + 16 + li] = f2b(ks1);
  }
  #pragma unroll
  for (int m = 0; m < 2; m++)
    #pragma unroll
    for (int n = 0; n < 2; n++) {
      int dd = n * 16 + li;
      int mg = wave * 32 + m * 16 + gi * 4;
      ushort4 pk;
      pk.x = f2b(cacc[m][n][0]); pk.y = f2b(cacc[m][n][1]);
      pk.z = f2b(cacc[m][n][2]); pk.w = f2b(cacc[m][n][3]);
      *(ushort4*)&Bmat[((size_t)bh * 48 + dd) * 128 + mg] = pk;
    }
  for (int e = tid; e < 15 * 128; e += 256)
    Bmat[((size_t)bh * 48 + 33) * 128 + e] = 0;
}

// ---------------- fused q-features + o per (64 t, bh) ----------------
__global__ __launch_bounds__(256) void favq_o(
    const ushort* __restrict__ qb, const ushort* __restrict__ projd,
    const ushort* __restrict__ Bmat, ushort* __restrict__ ob) {
  __shared__ __align__(16) ushort Ql[64 * 32];
  __shared__ __align__(16) ushort Pl[128 * 32];
  __shared__ __align__(16) ushort Sl[64 * 136];
  __shared__ __align__(16) ushort Bml[48 * 136];
  __shared__ float dgq[64];
  int bh = blockIdx.y;
  int t0 = blockIdx.x * 64;
  int b = bh >> 3, h = bh & 7;
  int tid = threadIdx.x, wave = tid >> 6, lane = tid & 63;
  int gi = lane >> 4, li = lane & 15;
  int lrow = lane >> 2, lkb = (lane & 3) * 8;
  const ushort* Qg = qb + (size_t)(b * 512) * 256 + h * 32;
  gload16(&Qg[(size_t)(t0 + wave * 16 + lrow) * 256 + lkb], &Ql[wave * 512]);
  #pragma unroll
  for (int i = 0; i < 2; i++) {
    int chunk = wave * 2 + i;
    gload16(&projd[(chunk * 16 + lrow) * 32 + lkb], &Pl[chunk * 512]);
  }
  #pragma unroll
  for (int j = 0; j < 3; j++) {
    int c = j * 256 + tid;
    int r = c >> 4, g = c & 15;
    *(uint4*)&Bml[r * 136 + g * 8] = *(const uint4*)&Bmat[(size_t)bh * 48 * 128 + r * 128 + g * 8];
  }
  __syncthreads();
  if (tid < 64) {
    const ushort* qr = &Ql[tid * 32];
    float s = 0.f;
    #pragma unroll
    for (int j = 0; j < 32; j++) { float v = bf2f(qr[j]); s += v * v; }
    dgq[tid] = DN2H * s;
  }
  short8 bq = *(const short8*)&Ql[(wave * 16 + li) * 32 + gi * 8];
  f32x4 sacc[8] = {};
  #pragma unroll
  for (int m = 0; m < 8; m++) {
    short8 a = *(const short8*)&Pl[(m * 16 + li) * 32 + gi * 8];
    sacc[m] = MFMA(a, bq, sacc[m]);
  }
  __syncthreads();
  float mx = -1e30f;
  #pragma unroll
  for (int m = 0; m < 8; m++)
    #pragma unroll
    for (int r = 0; r < 4; r++) mx = fmaxf(mx, sacc[m][r]);
  mx = fmaxf(mx, __shfl_xor(mx, 16));
  mx = fmaxf(mx, __shfl_xor(mx, 32));
  float dg = dgq[wave * 16 + li];
  #pragma unroll
  for (int m = 0; m < 8; m++) {
    ushort4 o4;
    #pragma unroll
    for (int r = 0; r < 4; r++)
      ((ushort*)&o4)[r] = f2b(RATIO * (__expf(sacc[m][r] - dg - mx) + KEPS));
    *(ushort4*)&Sl[(wave * 16 + li) * 136 + m * 16 + gi * 4] = o4;
  }
  __syncthreads();
  f32x4 oacc[3] = {};
  #pragma unroll
  for (int ks = 0; ks < 4; ks++) {
    short8 a = *(const short8*)&Sl[(wave * 16 + li) * 136 + ks * 32 + gi * 8];
    #pragma unroll
    for (int n = 0; n < 3; n++) {
      short8 bb = *(const short8*)&Bml[(n * 16 + li) * 136 + ks * 32 + gi * 8];
      oacc[n] = MFMA(a, bb, oacc[n]);
    }
  }
  int t = t0 + wave * 16 + gi * 4;
  float den[4];
  #pragma unroll
  for (int r = 0; r < 4; r++) den[r] = __shfl(oacc[2][r], lane & 48);
  #pragma unroll
  for (int n = 0; n < 2; n++)
    #pragma unroll
    for (int r = 0; r < 4; r++)
      ob[((size_t)(b * 512) + t + r) * 256 + h * 32 + n * 16 + li] = f2b(oacc[n][r] / den[r]);
}

// ---------------- fused Wo-GEMM + LN + FF1 (barrier-free per-wave pipelines) ----------------
__global__ __launch_bounds__(256) void wo_ff1(
    const ushort* __restrict__ ob, const ushort* __restrict__ woT,
    const float* __restrict__ bo, const float* __restrict__ res, float* __restrict__ x,
    const float* __restrict__ g, const float* __restrict__ bvec,
    const ushort* __restrict__ w1T, const float* __restrict__ b1v,
    ushort* __restrict__ ffh) {
  __shared__ __align__(16) ushort Apr[4][2][1024];   // per-wave A dbuf (32x32)
  __shared__ __align__(16) ushort Bpr[4][2][2048];   // per-wave B dbuf (64x32)
  __shared__ __align__(16) ushort Hp[8 * 1024];      // 16KB shared h panel
  __shared__ float rs1[4 * 32], rs2[4 * 32];
  int tid = threadIdx.x, wave = tid >> 6, lane = tid & 63;
  int gi = lane >> 4, li = lane & 15;
  int lrow = lane >> 2, lkb = SWZG(lane);
  int row0 = blockIdx.x * 32;
  f32x4 acc[2][4] = {};

  // ---- phase 1: Wo GEMM, K=256, wave-private staging, no barriers ----
  auto stage1 = [&](int buf, int kk) {
    #pragma unroll
    for (int i = 0; i < 2; i++)
      gload16(&ob[(size_t)(row0 + i * 16 + lrow) * 256 + kk + lkb], &Apr[wave][buf][i * 512]);
    #pragma unroll
    for (int i = 0; i < 4; i++)
      gload16(&woT[(size_t)(wave * 64 + i * 16 + lrow) * 256 + kk + lkb], &Bpr[wave][buf][i * 512]);
  };
  stage1(0, 0);
  int cur = 0;
  for (int k0 = 0; k0 < 256; k0 += 32, cur ^= 1) {
    if (k0 + 32 < 256) { stage1(cur ^ 1, k0 + 32); WAIT_VM(6); }
    else { WAIT_VM(0); }
    __builtin_amdgcn_sched_barrier(0);
    short8 a[2], b[4];
    #pragma unroll
    for (int m = 0; m < 2; m++)
      a[m] = *(const short8*)&Apr[wave][cur][(m * 16 + li) * 32 + RS(li, gi)];
    #pragma unroll
    for (int n = 0; n < 4; n++)
      b[n] = *(const short8*)&Bpr[wave][cur][(n * 16 + li) * 32 + RS(li, gi)];
    #pragma unroll
    for (int m = 0; m < 2; m++)
      #pragma unroll
      for (int n = 0; n < 4; n++)
        acc[m][n] = MFMA(a[m], b[n], acc[m][n]);
  }
  // epilogue A: bias+res, partial sums
  #pragma unroll
  for (int m = 0; m < 2; m++) {
    #pragma unroll
    for (int r = 0; r < 4; r++) {
      int row = row0 + m * 16 + gi * 4 + r;
      int ridx = m * 16 + gi * 4 + r;
      float s1 = 0.f, s2 = 0.f;
      #pragma unroll
      for (int n = 0; n < 4; n++) {
        int col = wave * 64 + n * 16 + li;
        float val = acc[m][n][r] + bo[col] + res[(size_t)row * 256 + col];
        acc[m][n][r] = val;
        s1 += val; s2 += val * val;
      }
      #pragma unroll
      for (int off = 1; off <= 8; off <<= 1) { s1 += __shfl_xor(s1, off); s2 += __shfl_xor(s2, off); }
      if (li == 0) { rs1[wave * 32 + ridx] = s1; rs2[wave * 32 + ridx] = s2; }
    }
  }
  __syncthreads();
  // epilogue B: LN -> x fp32 + Hp panel
  {
    float g4[4], bv4[4];
    #pragma unroll
    for (int n = 0; n < 4; n++) {
      int col = wave * 64 + n * 16 + li;
      g4[n] = g[col]; bv4[n] = bvec[col];
    }
    #pragma unroll
    for (int m = 0; m < 2; m++) {
      #pragma unroll
      for (int r = 0; r < 4; r++) {
        int row32 = m * 16 + gi * 4 + r;
        int row = row0 + row32;
        float t1 = rs1[row32] + rs1[32 + row32] + rs1[64 + row32] + rs1[96 + row32];
        float t2 = rs2[row32] + rs2[32 + row32] + rs2[64 + row32] + rs2[96 + row32];
        float mu = t1 * (1.f / 256.f);
        float rstd = rsqrtf(t2 * (1.f / 256.f) - mu * mu + 1e-5f);
        #pragma unroll
        for (int n = 0; n < 4; n++) {
          int col = wave * 64 + n * 16 + li;
          float val = acc[m][n][r];
          x[(size_t)row * 256 + col] = val;
          float hv = (val - mu) * rstd * g4[n] + bv4[n];
          int kc = col >> 5, c32 = col & 31;
          int G = c32 >> 3, c7 = c32 & 7;
          int slot = (G - (row32 >> 1)) & 3;
          Hp[kc * 1024 + row32 * 32 + slot * 8 + c7] = f2b(hv);
        }
      }
    }
  }
  // ---- phase 2: FF1 from Hp panel, wave-private B staging, no barriers ----
  auto stage2 = [&](int buf, int st) {
    int nc = st >> 3, ks = st & 7;
    #pragma unroll
    for (int i = 0; i < 4; i++)
      gload16(&w1T[(size_t)(nc * 256 + wave * 64 + i * 16 + lrow) * 256 + ks * 32 + lkb],
              &Bpr[wave][buf][i * 512]);
  };
  stage2(0, 0);
  __syncthreads();   // Hp visible to all waves
  cur = 0;
  f32x4 fac[2][4] = {};
  for (int st = 0; st < 32; st++, cur ^= 1) {
    int nc = st >> 3, ks = st & 7;
    if (st + 1 < 32) { stage2(cur ^ 1, st + 1); WAIT_VM(4); }
    else { WAIT_VM(0); }
    __builtin_amdgcn_sched_barrier(0);
    short8 a[2], b[4];
    #pragma unroll
    for (int m = 0; m < 2; m++)
      a[m] = *(const short8*)&Hp[ks * 1024 + (m * 16 + li) * 32 + RS(li, gi)];
    #pragma unroll
    for (int n = 0; n < 4; n++)
      b[n] = *(const short8*)&Bpr[wave][cur][(n * 16 + li) * 32 + RS(li, gi)];
    #pragma unroll
    for (int m = 0; m < 2; m++)
      #pragma unroll
      for (int n = 0; n < 4; n++)
        fac[m][n] = MFMA(a[m], b[n], fac[m][n]);
    if (ks == 7) {
      #pragma unroll
      for (int m = 0; m < 2; m++) {
        int rbase = row0 + m * 16 + gi * 4;
        #pragma unroll
        for (int n = 0; n < 4; n++) {
          int col = nc * 256 + wave * 64 + n * 16 + li;
          float bs = b1v[col];
          #pragma unroll
          for (int r = 0; r < 4; r++) {
            float u = fac[m][n][r] + bs;
            float p = u + 0.044715f * u * u * u;
            float gel = u / (1.0f + __expf(-1.5957691216057308f * p));
            ffh[(size_t)(rbase + r) * 1024 + col] = f2b(gel);
            fac[m][n][r] = 0.f;
          }
        }
      }
    }
  }
}

// ---------------- fused FF2-GEMM + LN + next-layer QKV (barrier-free pipelines) ----------------
__global__ __launch_bounds__(256) void ff2_qkv(
    const ushort* __restrict__ ffh, const ushort* __restrict__ w2T,
    const float* __restrict__ b2v, const float* __restrict__ res, float* __restrict__ x,
    const float* __restrict__ g, const float* __restrict__ bvec,
    const ushort* __restrict__ qkvT,
    ushort* __restrict__ qo, ushort* __restrict__ ko, ushort* __restrict__ vT) {
  __shared__ __align__(16) ushort Apr[4][2][1024];
  __shared__ __align__(16) ushort Bpr[4][2][2048];
  __shared__ __align__(16) ushort Hp[8 * 1024];
  __shared__ float rs1[4 * 32], rs2[4 * 32];
  int tid = threadIdx.x, wave = tid >> 6, lane = tid & 63;
  int gi = lane >> 4, li = lane & 15;
  int lrow = lane >> 2, lkb = SWZG(lane);
  int row0 = blockIdx.x * 32;
  f32x4 acc[2][4] = {};

  // ---- phase 1: FF2 GEMM, K=1024, wave-private staging, no barriers ----
  auto stage1 = [&](int buf, int kk) {
    #pragma unroll
    for (int i = 0; i < 2; i++)
      gload16(&ffh[(size_t)(row0 + i * 16 + lrow) * 1024 + kk + lkb], &Apr[wave][buf][i * 512]);
    #pragma unroll
    for (int i = 0; i < 4; i++)
      gload16(&w2T[(size_t)(wave * 64 + i * 16 + lrow) * 1024 + kk + lkb], &Bpr[wave][buf][i * 512]);
  };
  stage1(0, 0);
  int cur = 0;
  for (int k0 = 0; k0 < 1024; k0 += 32, cur ^= 1) {
    if (k0 + 32 < 1024) { stage1(cur ^ 1, k0 + 32); WAIT_VM(6); }
    else { WAIT_VM(0); }
    __builtin_amdgcn_sched_barrier(0);
    short8 a[2], b[4];
    #pragma unroll
    for (int m = 0; m < 2; m++)
      a[m] = *(const short8*)&Apr[wave][cur][(m * 16 + li) * 32 + RS(li, gi)];
    #pragma unroll
    for (int n = 0; n < 4; n++)
      b[n] = *(const short8*)&Bpr[wave][cur][(n * 16 + li) * 32 + RS(li, gi)];
    #pragma unroll
    for (int m = 0; m < 2; m++)
      #pragma unroll
      for (int n = 0; n < 4; n++)
        acc[m][n] = MFMA(a[m], b[n], acc[m][n]);
  }
  #pragma unroll
  for (int m = 0; m < 2; m++) {
    #pragma unroll
    for (int r = 0; r < 4; r++) {
      int row = row0 + m * 16 + gi * 4 + r;
      int ridx = m * 16 + gi * 4 + r;
      float s1 = 0.f, s2 = 0.f;
      #pragma unroll
      for (int n = 0; n < 4; n++) {
        int col = wave * 64 + n * 16 + li;
        float val = acc[m][n][r] + b2v[col] + res[(size_t)row * 256 + col];
        acc[m][n][r] = val;
        s1 += val; s2 += val * val;
      }
      #pragma unroll
      for (int off = 1; off <= 8; off <<= 1) { s1 += __shfl_xor(s1, off); s2 += __shfl_xor(s2, off); }
      if (li == 0) { rs1[wave * 32 + ridx] = s1; rs2[wave * 32 + ridx] = s2; }
    }
  }
  __syncthreads();
  {
    float g4[4], bv4[4];
    #pragma unroll
    for (int n = 0; n < 4; n++) {
      int col = wave * 64 + n * 16 + li;
      g4[n] = g[col]; bv4[n] = bvec[col];
    }
    #pragma unroll
    for (int m = 0; m < 2; m++) {
      #pragma unroll
      for (int r = 0; r < 4; r++) {
        int row32 = m * 16 + gi * 4 + r;
        int row = row0 + row32;
        float t1 = rs1[row32] + rs1[32 + row32] + rs1[64 + row32] + rs1[96 + row32];
        float t2 = rs2[row32] + rs2[32 + row32] + rs2[64 + row32] + rs2[96 + row32];
        float mu = t1 * (1.f / 256.f);
        float rstd = rsqrtf(t2 * (1.f / 256.f) - mu * mu + 1e-5f);
        #pragma unroll
        for (int n = 0; n < 4; n++) {
          int col = wave * 64 + n * 16 + li;
          float val = acc[m][n][r];
          x[(size_t)row * 256 + col] = val;
          float hv = (val - mu) * rstd * g4[n] + bv4[n];
          int kc = col >> 5, c32 = col & 31;
          int G = c32 >> 3, c7 = c32 & 7;
          int slot = (G - (row32 >> 1)) & 3;
          Hp[kc * 1024 + row32 * 32 + slot * 8 + c7] = f2b(hv);
        }
      }
    }
  }
  // ---- phase 2: QKV from Hp panel (N=768), wave-private B staging ----
  auto stage2 = [&](int buf, int st) {
    int nc = st >> 3, ks = st & 7;
    #pragma unroll
    for (int i = 0; i < 4; i++)
      gload16(&qkvT[(size_t)(nc * 256 + wave * 64 + i * 16 + lrow) * 256 + ks * 32 + lkb],
              &Bpr[wave][buf][i * 512]);
  };
  stage2(0, 0);
  __syncthreads();
  cur = 0;
  f32x4 fac[2][4] = {};
  for (int st = 0; st < 24; st++, cur ^= 1) {
    int nc = st >> 3, ks = st & 7;
    if (st + 1 < 24) { stage2(cur ^ 1, st + 1); WAIT_VM(4); }
    else { WAIT_VM(0); }
    __builtin_amdgcn_sched_barrier(0);
    short8 a[2], b[4];
    #pragma unroll
    for (int m = 0; m < 2; m++)
      a[m] = *(const short8*)&Hp[ks * 1024 + (m * 16 + li) * 32 + RS(li, gi)];
    #pragma unroll
    for (int n = 0; n < 4; n++)
      b[n] = *(const short8*)&Bpr[wave][cur][(n * 16 + li) * 32 + RS(li, gi)];
    #pragma unroll
    for (int m = 0; m < 2; m++)
      #pragma unroll
      for (int n = 0; n < 4; n++)
        fac[m][n] = MFMA(a[m], b[n], fac[m][n]);
    if (ks == 7) {
      #pragma unroll
      for (int m = 0; m < 2; m++) {
        int rbase = row0 + m * 16 + gi * 4;
        #pragma unroll
        for (int n = 0; n < 4; n++) {
          int col256 = wave * 64 + n * 16 + li;
          if (nc == 0) {
            #pragma unroll
            for (int r = 0; r < 4; r++) { qo[(size_t)(rbase + r) * 256 + col256] = f2b(fac[m][n][r]); fac[m][n][r] = 0.f; }
          } else if (nc == 1) {
            #pragma unroll
            for (int r = 0; r < 4; r++) { ko[(size_t)(rbase + r) * 256 + col256] = f2b(fac[m][n][r]); fac[m][n][r] = 0.f; }
          } else {
            int b_ = rbase >> 9, t = rbase & 511;
            int hh = col256 >> 5, d = col256 & 31;
            ushort4 pk;
            pk.x = f2b(fac[m][n][0]); pk.y = f2b(fac[m][n][1]);
            pk.z = f2b(fac[m][n][2]); pk.w = f2b(fac[m][n][3]);
            *(ushort4*)&vT[((size_t)((b_ * 8 + hh) * 32 + d)) * 512 + t] = pk;
            fac[m][n][0] = fac[m][n][1] = fac[m][n][2] = fac[m][n][3] = 0.f;
          }
        }
      }
    }
  }
}

// ---------------- GEMM 32x256 + bias + residual + mask (final layer FF2) ----------------
__global__ __launch_bounds__(256) void gemm_mask(
    const ushort* __restrict__ A, const ushort* __restrict__ BTm,
    const float* __restrict__ bias, const float* __restrict__ res,
    const float* __restrict__ Wm, const float* __restrict__ bm, float* __restrict__ mout,
    int K) {
  __shared__ __align__(16) ushort Al[2][32 * 32];
  __shared__ __align__(16) ushort Bl[2][256 * 32];
  __shared__ float pmS[4 * 128];
  int tid = threadIdx.x, wave = tid >> 6, lane = tid & 63;
  int gi = lane >> 4, li = lane & 15;
  int lrow = lane >> 2, lkb = SWZG(lane);
  int row0 = blockIdx.x * 32;
  int wc = wave;
  f32x4 acc[2][4] = {};

  auto stage = [&](int buf, int kk) {
    if (wave < 2)
      gload16(&A[(size_t)(row0 + wave * 16 + lrow) * K + kk + lkb], &Al[buf][wave * 512]);
    #pragma unroll
    for (int i = 0; i < 4; i++) {
      int chunk = wave * 4 + i;
      gload16(&BTm[(size_t)(chunk * 16 + lrow) * K + kk + lkb], &Bl[buf][chunk * 512]);
    }
  };
  stage(0, 0);
  __syncthreads();
  int cur = 0;
  for (int k0 = 0; k0 < K; k0 += 32, cur ^= 1) {
    if (k0 + 32 < K) stage(cur ^ 1, k0 + 32);
    short8 a[2], b[4];
    #pragma unroll
    for (int m = 0; m < 2; m++)
      a[m] = *(const short8*)&Al[cur][(m * 16 + li) * 32 + RS(li, gi)];
    #pragma unroll
    for (int n = 0; n < 4; n++)
      b[n] = *(const short8*)&Bl[cur][(wc * 64 + n * 16 + li) * 32 + RS(li, gi)];
    #pragma unroll
    for (int m = 0; m < 2; m++)
      #pragma unroll
      for (int n = 0; n < 4; n++)
        acc[m][n] = MFMA(a[m], b[n], acc[m][n]);
    __syncthreads();
  }
  #pragma unroll
  for (int m = 0; m < 2; m++) {
    #pragma unroll
    for (int r = 0; r < 4; r++) {
      int row = row0 + m * 16 + gi * 4 + r;
      int ridx = m * 16 + gi * 4 + r;
      #pragma unroll
      for (int n = 0; n < 4; n++) {
        int col = wc * 64 + n * 16 + li;
        acc[m][n][r] += bias[col] + res[(size_t)row * 256 + col];
      }
      #pragma unroll
      for (int msk = 0; msk < NM; msk++) {
        float sm = 0.f;
        #pragma unroll
        for (int n = 0; n < 4; n++) {
          int col = wc * 64 + n * 16 + li;
          sm += acc[m][n][r] * Wm[col * NM + msk];
        }
        #pragma unroll
        for (int off = 1; off <= 8; off <<= 1) sm += __shfl_xor(sm, off);
        if (li == 0) pmS[wave * 128 + ridx * 4 + msk] = sm;
      }
    }
  }
  __syncthreads();
  if (tid < 128) {
    int ridx = tid >> 2, msk = tid & 3;
    float tot = pmS[ridx * 4 + msk] + pmS[128 + ridx * 4 + msk] +
                pmS[256 + ridx * 4 + msk] + pmS[384 + ridx * 4 + msk];
    int grow = row0 + ridx;
    int bb_ = grow >> 9, t = grow & 511;
    mout[((size_t)(bb_ * NM) + msk) * 512 + t] = tot + bm[msk];
  }
}

extern "C" void kernel_launch(void* const* d_in, const int* in_sizes, int n_in,
                              void* d_out, int out_size, void* d_ws, size_t ws_size,
                              hipStream_t stream) {
  const float* mel   = (const float*)d_in[0];
  const float* proj  = (const float*)d_in[1];
  const float* ln1_g = (const float*)d_in[2];
  const float* ln1_b = (const float*)d_in[3];
  const float* Wq    = (const float*)d_in[4];
  const float* Wk    = (const float*)d_in[5];
  const float* Wv    = (const float*)d_in[6];
  const float* Wo    = (const float*)d_in[7];
  const float* bo    = (const float*)d_in[8];
  const float* ln2_g = (const float*)d_in[9];
  const float* ln2_b = (const float*)d_in[10];
  const float* W1    = (const float*)d_in[11];
  const float* b1    = (const float*)d_in[12];
  const float* W2    = (const float*)d_in[13];
  const float* b2    = (const float*)d_in[14];
  const float* Wm    = (const float*)d_in[15];
  const float* bm    = (const float*)d_in[16];

  // ---- workspace layout ----
  float* x      = (float*)d_ws;                        // BT*D fp32
  ushort* us    = (ushort*)(x + (size_t)BT * D);
  ushort* h     = us;                   us += (size_t)BT * D;
  ushort* qb    = us;                   us += (size_t)BT * D;
  ushort* kb    = us;                   us += (size_t)BT * D;
  ushort* vT    = us;                   us += (size_t)BH * 32 * T;
  ushort* ob    = us;                   us += (size_t)BT * D;
  ushort* ffh   = us;                   us += (size_t)BT * FF;
  ushort* Bmat  = us;                   us += (size_t)BH * 48 * MF;
  ushort* qkvT  = us;                   us += (size_t)NLAYER * 768 * 256;
  ushort* woT   = us;                   us += (size_t)NLAYER * 256 * 256;
  ushort* w1T   = us;                   us += (size_t)NLAYER * 1024 * 256;
  ushort* w2T   = us;                   us += (size_t)NLAYER * 256 * 1024;
  ushort* projd = us;                   us += (size_t)MF * DH;

  // ---- prep: transposed bf16 weights ----
  wtrans<<<dim3(8, 8, NLAYER), dim3(32, 8), 0, stream>>>(Wq, qkvT, 256, 256, 65536, 768 * 256);
  wtrans<<<dim3(8, 8, NLAYER), dim3(32, 8), 0, stream>>>(Wk, qkvT + 256 * 256, 256, 256, 65536, 768 * 256);
  wtrans<<<dim3(8, 8, NLAYER), dim3(32, 8), 0, stream>>>(Wv, qkvT + 512 * 256, 256, 256, 65536, 768 * 256);
  wtrans<<<dim3(8, 8, NLAYER), dim3(32, 8), 0, stream>>>(Wo, woT, 256, 256, 65536, 65536);
  wtrans<<<dim3(32, 8, NLAYER), dim3(32, 8), 0, stream>>>(W1, w1T, 256, 1024, 262144, 262144);
  wtrans<<<dim3(8, 32, NLAYER), dim3(32, 8), 0, stream>>>(W2, w2T, 1024, 256, 262144, 262144);
  proj_conv<<<16, 256, 0, stream>>>(proj, projd);

  transpose_mel<<<dim3(T / 32, D / 32, B), dim3(32, 8), 0, stream>>>(mel, x);
  ln_kernel<<<BT / 4, 256, 0, stream>>>(x, ln1_g, ln1_b, h);

  // layer-0 QKV from global h
  gemm_bf16<0, 64><<<dim3(6, 256), 256, 0, stream>>>(h, qkvT,
      nullptr, nullptr, qb, kb, vT, 768, 256);

  for (int l = 0; l < NLAYER; l++) {
    ctx_fused<<<BH, 256, 0, stream>>>(kb, projd, vT, Bmat);
    favq_o<<<dim3(8, BH), 256, 0, stream>>>(qb, projd, Bmat, ob);
    wo_ff1<<<BT / 32, 256, 0, stream>>>(ob, woT + (size_t)l * 256 * 256,
        bo + l * D, x, x, ln2_g + l * D, ln2_b + l * D,
        w1T + (size_t)l * 1024 * 256, b1 + (size_t)l * FF, ffh);
    if (l < NLAYER - 1) {
      ff2_qkv<<<BT / 32, 256, 0, stream>>>(ffh, w2T + (size_t)l * 256 * 1024,
          b2 + l * D, x, x, ln1_g + (l + 1) * D, ln1_b + (l + 1) * D,
          qkvT + (size_t)(l + 1) * 768 * 256, qb, kb, vT);
    } else {
      gemm_mask<<<BT / 32, 256, 0, stream>>>(ffh, w2T + (size_t)l * 256 * 1024,
          b2 + l * D, x, Wm, bm, (float*)d_out, 1024);
    }
  }
}